// Round 1
// baseline (241.108 us; speedup 1.0000x reference)
//
#include <hip/hip_runtime.h>

#define NSAMP 131072
#define DIMS 8
#define NPCE 495
#define KP 512          // K padded to 512
#define NOUT 256
#define BM 64           // samples per block
#define TK 128          // K-tile held in LDS
#define PSI_STRIDE 136  // TK + 8 bf16: row stride 272B -> 2-way (free) b128 conflicts
#define H_STRIDE 41     // 40 + 1 floats

typedef __bf16 bf16x8 __attribute__((ext_vector_type(8)));
typedef float f32x4 __attribute__((ext_vector_type(4)));

__device__ __forceinline__ unsigned short f2bf(float f) {
    unsigned int u = __float_as_uint(f);
    unsigned int r = (u + 0x7fffu + ((u >> 16) & 1u)) >> 16;  // RTNE
    return (unsigned short)r;
}

// Pre-kernel: weight f32 [256][495] -> bf16 [256][512] (zero-padded K),
// and mi [495][8] -> packed u32 of up to 4 (dim*5+ord) 6-bit H-indices.
__global__ __launch_bounds__(256) void prep_kernel(const float* __restrict__ w,
                                                   const int* __restrict__ mi,
                                                   unsigned short* __restrict__ wb,
                                                   unsigned int* __restrict__ pk) {
    int t = blockIdx.x * 256 + threadIdx.x;
    if (t < NOUT * KP) {
        int o = t >> 9;          // t / 512
        int k = t & (KP - 1);
        float v = (k < NPCE) ? w[o * NPCE + k] : 0.0f;
        wb[t] = f2bf(v);
    }
    if (t < KP) {
        unsigned int code = 0;   // unused slots -> index 0 -> H[d0][ord0] == 1
        int slot = 0;
        if (t < NPCE) {
            for (int j = 0; j < DIMS; ++j) {
                int o = mi[t * DIMS + j];
                if (o != 0) {
                    code |= ((unsigned int)(j * 5 + o)) << (6 * slot);
                    ++slot;
                }
            }
        }
        pk[t] = code;
    }
}

// Main: per block of 64 samples: Hermite H in LDS, psi K-tiles in LDS (bf16),
// 16x16x32 bf16 MFMA against L2-resident bf16 weight (native B^T layout).
__global__ __launch_bounds__(256, 3) void pce_kernel(const float* __restrict__ x,
                                                     const unsigned short* __restrict__ wb,
                                                     const unsigned int* __restrict__ pk,
                                                     float* __restrict__ out) {
    __shared__ float Hl[BM * H_STRIDE];                                    // 10.5 KB
    __shared__ __attribute__((aligned(16))) unsigned short Psi[BM * PSI_STRIDE]; // 17.4 KB

    const int tid = threadIdx.x;
    const int lane = tid & 63;
    const int wave = tid >> 6;    // 0..3 -> output-column quarter
    const int quad = lane >> 4;
    const int l15 = lane & 15;
    const int m0 = blockIdx.x * BM;

    // ---- Phase A: normalized probabilists' Hermite basis into LDS ----
    const float rn2 = 0.70710678118654752f;  // 1/sqrt(2!)
    const float rn3 = 0.40824829046386302f;  // 1/sqrt(3!)
    const float rn4 = 0.20412414523193151f;  // 1/sqrt(4!)
    for (int p = tid; p < BM * DIMS; p += 256) {
        int s = p >> 3;
        int d = p & 7;
        float xv = x[(m0 + s) * DIMS + d];
        float h1 = xv;
        float h2 = xv * h1 - 1.0f;
        float h3 = xv * h2 - 2.0f * h1;
        float h4 = xv * h3 - 3.0f * h2;
        float* Hp = &Hl[s * H_STRIDE + d * 5];
        Hp[0] = 1.0f;
        Hp[1] = h1;
        Hp[2] = h2 * rn2;
        Hp[3] = h3 * rn3;
        Hp[4] = h4 * rn4;
    }

    f32x4 acc[4][4] = {};

    const int kl = tid & (TK - 1);   // k within tile (0..127)
    const int strip = tid >> 7;      // 0..1 -> 32-sample strip

    for (int kt = 0; kt < KP / TK; ++kt) {
        __syncthreads();  // H ready (iter 0) / prior MFMA done consuming Psi
        // ---- psi tile: thread owns one k, 32 samples ----
        unsigned int code = pk[kt * TK + kl];
        const int i0 = code & 63;
        const int i1 = (code >> 6) & 63;
        const int i2 = (code >> 12) & 63;
        const int i3 = (code >> 18) & 63;
        for (int s = strip * 32; s < strip * 32 + 32; ++s) {
            const float* Hs = &Hl[s * H_STRIDE];
            float pr = Hs[i0] * Hs[i1] * Hs[i2] * Hs[i3];
            Psi[s * PSI_STRIDE + kl] = f2bf(pr);
        }
        __syncthreads();  // Psi ready
        // ---- MFMA over this K-tile ----
        #pragma unroll
        for (int ks = 0; ks < TK / 32; ++ks) {
            bf16x8 af[4], bfr[4];
            #pragma unroll
            for (int im = 0; im < 4; ++im) {
                const unsigned short* ap =
                    &Psi[(im * 16 + l15) * PSI_STRIDE + ks * 32 + quad * 8];
                af[im] = *(const bf16x8*)ap;  // ds_read_b128
            }
            #pragma unroll
            for (int in = 0; in < 4; ++in) {
                int n = wave * 64 + in * 16 + l15;
                const unsigned short* bp = &wb[n * KP + kt * TK + ks * 32 + quad * 8];
                bfr[in] = *(const bf16x8*)bp;  // global_load_dwordx4, L2-hot
            }
            #pragma unroll
            for (int im = 0; im < 4; ++im)
                #pragma unroll
                for (int in = 0; in < 4; ++in)
                    acc[im][in] = __builtin_amdgcn_mfma_f32_16x16x32_bf16(
                        af[im], bfr[in], acc[im][in], 0, 0, 0);
        }
    }

    // ---- epilogue: D[row][col], row = quad*4 + i, col = lane&15 ----
    #pragma unroll
    for (int im = 0; im < 4; ++im) {
        #pragma unroll
        for (int i = 0; i < 4; ++i) {
            int m = m0 + im * 16 + quad * 4 + i;
            float* op = &out[m * NOUT + wave * 64 + l15];
            #pragma unroll
            for (int in = 0; in < 4; ++in)
                op[in * 16] = acc[im][in][i];
        }
    }
}

extern "C" void kernel_launch(void* const* d_in, const int* in_sizes, int n_in,
                              void* d_out, int out_size, void* d_ws, size_t ws_size,
                              hipStream_t stream) {
    const float* x = (const float*)d_in[0];
    const float* w = (const float*)d_in[1];
    const int* mi = (const int*)d_in[2];
    float* out = (float*)d_out;

    unsigned short* wb = (unsigned short*)d_ws;                       // 256*512*2 = 256 KB
    unsigned int* pk = (unsigned int*)((char*)d_ws + NOUT * KP * 2);  // 512*4 = 2 KB

    prep_kernel<<<(NOUT * KP + 255) / 256, 256, 0, stream>>>(w, mi, wb, pk);
    pce_kernel<<<NSAMP / BM, 256, 0, stream>>>(x, wb, pk, out);
}

// Round 3
// 202.517 us; speedup vs baseline: 1.1906x; 1.1906x over previous
//
#include <hip/hip_runtime.h>

#define NSAMP 131072
#define DIMS 8
#define NPCE 495
#define KP 512          // K padded to 512
#define NOUT 256
#define BM 64           // samples per block
#define TK 128          // K-tile in LDS
#define NH 70           // half-products per 4-dim half (order<=4)
#define HS 72           // At/Bt sample stride: 144B = 9 x 16B (odd granules)

typedef __bf16 bf16x8 __attribute__((ext_vector_type(8)));
typedef float f32x4 __attribute__((ext_vector_type(4)));
typedef unsigned short u16x8 __attribute__((ext_vector_type(8)));

__device__ __forceinline__ unsigned short f2bf(float f) {
    unsigned int u = __float_as_uint(f);
    unsigned int r = (u + 0x7fffu + ((u >> 16) & 1u)) >> 16;  // RTNE
    return (unsigned short)r;
}

__device__ __forceinline__ float bfbits2f(unsigned short u) {
    union { unsigned int i; float f; } c;
    c.i = ((unsigned int)u) << 16;
    return c.f;
}

__device__ __forceinline__ unsigned int pack2bf(float a, float b) {
    return (unsigned int)f2bf(a) | ((unsigned int)f2bf(b) << 16);
}

// Rank of 4-dim multi-index (sum<=4) in the canonical nest enumeration.
__device__ int rank4(int a0, int a1, int a2, int a3) {
    int idx = 0;
    for (int b0 = 0; b0 <= 4; ++b0)
        for (int b1 = 0; b1 <= 4 - b0; ++b1)
            for (int b2 = 0; b2 <= 4 - b0 - b1; ++b2)
                for (int b3 = 0; b3 <= 4 - b0 - b1 - b2; ++b3) {
                    if (b0 == a0 && b1 == a1 && b2 == a2 && b3 == a3) return idx;
                    ++idx;
                }
    return 0;
}

// prep: weight f32 [256][495] -> bf16 [256][512]; mi[k][8] -> (h1 | h2<<8).
__global__ __launch_bounds__(256) void prep_kernel(const float* __restrict__ w,
                                                   const int* __restrict__ mi,
                                                   unsigned short* __restrict__ wb,
                                                   int* __restrict__ hcode) {
    int t = blockIdx.x * 256 + threadIdx.x;
    if (t < NOUT * KP) {
        int o = t >> 9;
        int k = t & (KP - 1);
        float v = (k < NPCE) ? w[o * NPCE + k] : 0.0f;
        wb[t] = f2bf(v);
    }
    if (t < KP) {
        int code = 0;
        if (t < NPCE) {
            const int* m = &mi[t * DIMS];
            int h1 = rank4(m[0], m[1], m[2], m[3]);
            int h2 = rank4(m[4], m[5], m[6], m[7]);
            code = h1 | (h2 << 8);
        }
        hcode[t] = code;
    }
}

// Build 35 of the 70 half-products (compile-time range -> full DCE/CSE).
template <int LO, int HI>
__device__ __forceinline__ void build_half(const float H0[5], const float H1[5],
                                           const float H2[5], const float H3[5],
                                           unsigned short* dst, int s) {
    int idx = 0;
    #pragma unroll
    for (int a0 = 0; a0 <= 4; ++a0)
        #pragma unroll
        for (int a1 = 0; a1 <= 4 - a0; ++a1)
            #pragma unroll
            for (int a2 = 0; a2 <= 4 - a0 - a1; ++a2)
                #pragma unroll
                for (int a3 = 0; a3 <= 4 - a0 - a1 - a2; ++a3) {
                    if (idx >= LO && idx < HI) {
                        float p = H0[a0] * H1[a1] * H2[a2] * H3[a3];
                        dst[idx * HS + s] = f2bf(p);
                    }
                    ++idx;
                }
}

__device__ __forceinline__ void hermite5(float x, float H[5]) {
    const float rn2 = 0.70710678118654752f;
    const float rn3 = 0.40824829046386302f;
    const float rn4 = 0.20412414523193151f;
    float r1 = x;
    float r2 = x * r1 - 1.0f;
    float r3 = x * r2 - 2.0f * r1;
    float r4 = x * r3 - 3.0f * r2;
    H[0] = 1.0f; H[1] = r1; H[2] = r2 * rn2; H[3] = r3 * rn3; H[4] = r4 * rn4;
}

__global__ __launch_bounds__(256, 3) void pce_kernel(const float* __restrict__ x,
                                                     const unsigned short* __restrict__ wb,
                                                     const int* __restrict__ hcode,
                                                     float* __restrict__ out) {
    // Transposed half-product tables + XOR-swizzled psi tile.
    __shared__ __attribute__((aligned(16))) unsigned short At[NH * HS];  // 10.1 KB
    __shared__ __attribute__((aligned(16))) unsigned short Bt[NH * HS];  // 10.1 KB
    __shared__ __attribute__((aligned(16))) unsigned short Psi[BM * 128]; // 16 KB

    const int tid = threadIdx.x;
    const int lane = tid & 63;
    const int wave = tid >> 6;
    const int quad = lane >> 4;
    const int l15 = lane & 15;
    const int m0 = blockIdx.x * BM;

    // Preload this thread's (h1,h2) codes for all 4 K-tiles (16B loads).
    const int t32 = tid & 31;
    const int sgrp = tid >> 5;
    const int s0 = sgrp * 8;
    int4 codes[4];
    {
        const int4* hc4 = (const int4*)hcode;
        #pragma unroll
        for (int kt = 0; kt < 4; ++kt) codes[kt] = hc4[kt * 32 + t32];
    }

    // ---- Builder: wave -> (half = wave>>1, term range = wave&1), lane = sample.
    {
        const int half = wave >> 1;
        const float4 xv = *(const float4*)&x[(m0 + lane) * DIMS + half * 4];
        float H0[5], H1[5], H2[5], H3[5];
        hermite5(xv.x, H0);
        hermite5(xv.y, H1);
        hermite5(xv.z, H2);
        hermite5(xv.w, H3);
        unsigned short* dst = half ? Bt : At;
        if (wave & 1) build_half<35, 70>(H0, H1, H2, H3, dst, lane);
        else          build_half<0, 35>(H0, H1, H2, H3, dst, lane);
    }
    __syncthreads();

    f32x4 acc[4][4] = {};

    for (int kt = 0; kt < KP / TK; ++kt) {
        // ---- Gather: thread owns 4 k x 8 samples. 8 b128 reads + 8 b64 writes.
        float pf[4][8];
        int4 cd = codes[kt];
        #pragma unroll
        for (int j = 0; j < 4; ++j) {
            int code = (&cd.x)[j];
            u16x8 av = *(const u16x8*)&At[(code & 255) * HS + s0];
            u16x8 bv = *(const u16x8*)&Bt[((code >> 8) & 255) * HS + s0];
            #pragma unroll
            for (int i = 0; i < 8; ++i)
                pf[j][i] = bfbits2f(av[i]) * bfbits2f(bv[i]);
        }
        #pragma unroll
        for (int i = 0; i < 8; ++i) {
            int s = s0 + i;
            uint2 wv;
            wv.x = pack2bf(pf[0][i], pf[1][i]);
            wv.y = pack2bf(pf[2][i], pf[3][i]);
            int gran = (t32 >> 1) ^ (s & 7);  // XOR swizzle (16B granules)
            *(uint2*)&Psi[s * 128 + gran * 8 + (t32 & 1) * 4] = wv;
        }
        __syncthreads();  // psi tile ready

        // ---- MFMA over tile: A frags from swizzled Psi, B frags from L2-hot wb.
        #pragma unroll
        for (int ks = 0; ks < TK / 32; ++ks) {
            bf16x8 af[4], bfr[4];
            #pragma unroll
            for (int im = 0; im < 4; ++im) {
                int row = im * 16 + l15;
                int kg = (ks * 4 + quad) ^ (row & 7);
                af[im] = *(const bf16x8*)&Psi[row * 128 + kg * 8];
            }
            #pragma unroll
            for (int in = 0; in < 4; ++in) {
                int n = wave * 64 + in * 16 + l15;
                const unsigned short* bp = &wb[n * KP + kt * TK + ks * 32 + quad * 8];
                bfr[in] = *(const bf16x8*)bp;
            }
            #pragma unroll
            for (int im = 0; im < 4; ++im)
                #pragma unroll
                for (int in = 0; in < 4; ++in)
                    acc[im][in] = __builtin_amdgcn_mfma_f32_16x16x32_bf16(
                        af[im], bfr[in], acc[im][in], 0, 0, 0);
        }
        __syncthreads();  // MFMA done reading Psi before next gather
    }

    // ---- epilogue: D[row][col], row = quad*4 + i, col = l15 ----
    #pragma unroll
    for (int im = 0; im < 4; ++im) {
        #pragma unroll
        for (int i = 0; i < 4; ++i) {
            int m = m0 + im * 16 + quad * 4 + i;
            float* op = &out[m * NOUT + wave * 64 + l15];
            #pragma unroll
            for (int in = 0; in < 4; ++in)
                op[in * 16] = acc[im][in][i];
        }
    }
}

extern "C" void kernel_launch(void* const* d_in, const int* in_sizes, int n_in,
                              void* d_out, int out_size, void* d_ws, size_t ws_size,
                              hipStream_t stream) {
    const float* x = (const float*)d_in[0];
    const float* w = (const float*)d_in[1];
    const int* mi = (const int*)d_in[2];
    float* out = (float*)d_out;

    unsigned short* wb = (unsigned short*)d_ws;                 // 256 KB
    int* hcode = (int*)((char*)d_ws + NOUT * KP * 2);           // 2 KB

    prep_kernel<<<(NOUT * KP + 255) / 256, 256, 0, stream>>>(w, mi, wb, hcode);
    pce_kernel<<<NSAMP / BM, 256, 0, stream>>>(x, wb, hcode, out);
}

// Round 4
// 196.408 us; speedup vs baseline: 1.2276x; 1.0311x over previous
//
#include <hip/hip_runtime.h>

#define NSAMP 131072
#define DIMS 8
#define NPCE 495
#define KP 512          // K padded to 512
#define NOUT 256
#define BM 64           // samples per block
#define SK 64           // K per pipeline stage
#define NSTG (KP / SK)  // 8 stages
#define NH 70           // half-products per 4-dim half (order<=4)
#define HS 68           // At/Bt sample stride: 136B, words==2 mod 32 -> banks spread by h
#define PS 72           // Psi row stride: 144B, words==4 mod 32 -> min-conflict writes+reads

typedef __bf16 bf16x8 __attribute__((ext_vector_type(8)));
typedef float f32x4 __attribute__((ext_vector_type(4)));
typedef unsigned short u16x4 __attribute__((ext_vector_type(4)));

__device__ __forceinline__ unsigned short f2bf(float f) {
    unsigned int u = __float_as_uint(f);
    unsigned int r = (u + 0x7fffu + ((u >> 16) & 1u)) >> 16;  // RTNE
    return (unsigned short)r;
}

__device__ __forceinline__ float bfbits2f(unsigned short u) {
    union { unsigned int i; float f; } c;
    c.i = ((unsigned int)u) << 16;
    return c.f;
}

__device__ __forceinline__ unsigned int pack2bf(float a, float b) {
    return (unsigned int)f2bf(a) | ((unsigned int)f2bf(b) << 16);
}

// Rank of 4-dim multi-index (sum<=4) in the canonical nest enumeration.
__device__ int rank4(int a0, int a1, int a2, int a3) {
    int idx = 0;
    for (int b0 = 0; b0 <= 4; ++b0)
        for (int b1 = 0; b1 <= 4 - b0; ++b1)
            for (int b2 = 0; b2 <= 4 - b0 - b1; ++b2)
                for (int b3 = 0; b3 <= 4 - b0 - b1 - b2; ++b3) {
                    if (b0 == a0 && b1 == a1 && b2 == a2 && b3 == a3) return idx;
                    ++idx;
                }
    return 0;
}

// prep: weight -> bf16 [256][512] with PERMUTED rows (epilogue dwordx4 stores):
// row n holds original column o = (n&~63) | ((n&15)<<2) | ((n>>4)&3).
// mi[k][8] -> u16 code h1 | (h2<<8).
__global__ __launch_bounds__(256) void prep_kernel(const float* __restrict__ w,
                                                   const int* __restrict__ mi,
                                                   unsigned short* __restrict__ wb,
                                                   unsigned short* __restrict__ hcode) {
    int t = blockIdx.x * 256 + threadIdx.x;
    if (t < NOUT * KP) {
        int n = t >> 9;
        int k = t & (KP - 1);
        int o = (n & ~63) | ((n & 15) << 2) | ((n >> 4) & 3);
        float v = (k < NPCE) ? w[o * NPCE + k] : 0.0f;
        wb[t] = f2bf(v);
    }
    if (t < KP) {
        int code = 0;
        if (t < NPCE) {
            const int* m = &mi[t * DIMS];
            int h1 = rank4(m[0], m[1], m[2], m[3]);
            int h2 = rank4(m[4], m[5], m[6], m[7]);
            code = h1 | (h2 << 8);
        }
        hcode[t] = (unsigned short)code;
    }
}

// Build 35 of the 70 half-products (compile-time range -> full DCE/CSE).
template <int LO, int HI>
__device__ __forceinline__ void build_half(const float H0[5], const float H1[5],
                                           const float H2[5], const float H3[5],
                                           unsigned short* dst, int s) {
    int idx = 0;
    #pragma unroll
    for (int a0 = 0; a0 <= 4; ++a0)
        #pragma unroll
        for (int a1 = 0; a1 <= 4 - a0; ++a1)
            #pragma unroll
            for (int a2 = 0; a2 <= 4 - a0 - a1; ++a2)
                #pragma unroll
                for (int a3 = 0; a3 <= 4 - a0 - a1 - a2; ++a3) {
                    if (idx >= LO && idx < HI) {
                        float p = H0[a0] * H1[a1] * H2[a2] * H3[a3];
                        dst[idx * HS + s] = f2bf(p);
                    }
                    ++idx;
                }
}

__device__ __forceinline__ void hermite5(float x, float H[5]) {
    const float rn2 = 0.70710678118654752f;
    const float rn3 = 0.40824829046386302f;
    const float rn4 = 0.20412414523193151f;
    float r1 = x;
    float r2 = x * r1 - 1.0f;
    float r3 = x * r2 - 2.0f * r1;
    float r4 = x * r3 - 3.0f * r2;
    H[0] = 1.0f; H[1] = r1; H[2] = r2 * rn2; H[3] = r3 * rn3; H[4] = r4 * rn4;
}

__global__ __launch_bounds__(256, 3) void pce_kernel(const float* __restrict__ x,
                                                     const unsigned short* __restrict__ wb,
                                                     const unsigned short* __restrict__ hcode,
                                                     float* __restrict__ out) {
    __shared__ __attribute__((aligned(16))) unsigned short At[NH * HS];    // 9.52 KB
    __shared__ __attribute__((aligned(16))) unsigned short Bt[NH * HS];    // 9.52 KB
    __shared__ __attribute__((aligned(16))) unsigned short Psi[2][BM * PS]; // 18.4 KB

    const int tid = threadIdx.x;
    const int lane = tid & 63;
    const int wave = tid >> 6;
    const int quad = lane >> 4;
    const int l15 = lane & 15;
    const int m0 = blockIdx.x * BM;

    // Gather mapping: thread owns 4 k (group u16k) x 4 samples (s0..s0+3).
    const int u16k = tid & 15;
    const int s0 = (tid >> 4) * 4;

    // ---- Builder: wave -> (half = wave>>1, term range = wave&1), lane = sample.
    {
        const int half = wave >> 1;
        const float4 xv = *(const float4*)&x[(m0 + lane) * DIMS + half * 4];
        float H0[5], H1[5], H2[5], H3[5];
        hermite5(xv.x, H0);
        hermite5(xv.y, H1);
        hermite5(xv.z, H2);
        hermite5(xv.w, H3);
        unsigned short* dst = half ? Bt : At;
        if (wave & 1) build_half<35, 70>(H0, H1, H2, H3, dst, lane);
        else          build_half<0, 35>(H0, H1, H2, H3, dst, lane);
    }

    f32x4 acc[4][4] = {};

    // Gather one 64-wide stage into Psi[buf]: 8 ds_read_b64 + VALU + 4 ds_write_b64.
    auto gather = [&](int stage, int buf) {
        u16x4 cds = *(const u16x4*)&hcode[stage * SK + u16k * 4];
        float pf[4][4];
        #pragma unroll
        for (int j = 0; j < 4; ++j) {
            int h1 = cds[j] & 255;
            int h2 = cds[j] >> 8;
            u16x4 av = *(const u16x4*)&At[h1 * HS + s0];
            u16x4 bv = *(const u16x4*)&Bt[h2 * HS + s0];
            #pragma unroll
            for (int i = 0; i < 4; ++i)
                pf[j][i] = bfbits2f(av[i]) * bfbits2f(bv[i]);
        }
        #pragma unroll
        for (int i = 0; i < 4; ++i) {
            uint2 wv;
            wv.x = pack2bf(pf[0][i], pf[1][i]);
            wv.y = pack2bf(pf[2][i], pf[3][i]);
            *(uint2*)&Psi[buf][(s0 + i) * PS + u16k * 4] = wv;
        }
    };

    __syncthreads();   // At/Bt ready
    gather(0, 0);

    #pragma unroll 2
    for (int s = 0; s < NSTG; ++s) {
        __syncthreads();  // Psi[s&1] writes visible; Psi[(s+1)&1] reads drained
        if (s < NSTG - 1) gather(s + 1, (s + 1) & 1);  // overlaps with MFMA below
        #pragma unroll
        for (int ks = 0; ks < SK / 32; ++ks) {
            bf16x8 af[4], bfr[4];
            #pragma unroll
            for (int im = 0; im < 4; ++im) {
                int row = im * 16 + l15;
                af[im] = *(const bf16x8*)&Psi[s & 1][row * PS + ks * 32 + quad * 8];
            }
            #pragma unroll
            for (int in = 0; in < 4; ++in) {
                int n = wave * 64 + in * 16 + l15;
                bfr[in] = *(const bf16x8*)&wb[n * KP + s * SK + ks * 32 + quad * 8];
            }
            #pragma unroll
            for (int im = 0; im < 4; ++im)
                #pragma unroll
                for (int in = 0; in < 4; ++in)
                    acc[im][in] = __builtin_amdgcn_mfma_f32_16x16x32_bf16(
                        af[im], bfr[in], acc[im][in], 0, 0, 0);
        }
    }

    // ---- epilogue: permuted weights make lane's 4 'in' values 4 consecutive
    // output columns -> coalesced dwordx4 stores (16 per thread).
    #pragma unroll
    for (int im = 0; im < 4; ++im) {
        #pragma unroll
        for (int i = 0; i < 4; ++i) {
            int m = m0 + im * 16 + quad * 4 + i;
            float4 v = make_float4(acc[im][0][i], acc[im][1][i],
                                   acc[im][2][i], acc[im][3][i]);
            *(float4*)&out[m * NOUT + wave * 64 + l15 * 4] = v;
        }
    }
}

extern "C" void kernel_launch(void* const* d_in, const int* in_sizes, int n_in,
                              void* d_out, int out_size, void* d_ws, size_t ws_size,
                              hipStream_t stream) {
    const float* x = (const float*)d_in[0];
    const float* w = (const float*)d_in[1];
    const int* mi = (const int*)d_in[2];
    float* out = (float*)d_out;

    unsigned short* wb = (unsigned short*)d_ws;                          // 256 KB
    unsigned short* hcode = (unsigned short*)((char*)d_ws + NOUT * KP * 2); // 1 KB

    prep_kernel<<<(NOUT * KP + 255) / 256, 256, 0, stream>>>(w, mi, wb, hcode);
    pce_kernel<<<NSAMP / BM, 256, 0, stream>>>(x, wb, hcode, out);
}